// Round 7
// baseline (165.653 us; speedup 1.0000x reference)
//
#include <hip/hip_runtime.h>

// Chamfer via MFMA: d2(n,m) = psq[n] + qsq[m] - 2*p.q computed ENTIRELY in
// one v_mfma_f32_32x32x16_bf16 per 32x32 tile, K slots (13 of 16 used):
//   k0 : psqh * 1       k1 : psql * 1
//   k2-4 : -2ph * qh    k5-7 : -2pl * qh    k8-10: -2ph * ql
//   k11: 1 * qsqh       k12: 1 * qsql       k13-15: 0
// (bf16 hi/lo split; dropped pl*ql term ~1e-5 relative -> well under tol.)
// Both chamfer directions come from the SAME d2 tiles: row-mins accumulate
// in registers (C layout: col=lane&31, row=(reg&3)+8*(reg>>2)+4*(lane>>5));
// col-mins go to a per-(batch,col) global atomicMin on float-as-uint
// (values clamped >=0 so uint order == float order).
// Grid: 128 batches x 8 blocks x 4 waves = 32 strips of 32 rows per batch;
// each wave loops 32 col-tiles. Packed A/B staged in LDS (hi/lo arrays,
// 4 x 16 KB); fragment reads are 16 B/lane sequential (conflict-free).
// k2: sweep 128K col-mins (512 KB), sqrt, sum, atomicAdd.

typedef short bf16x8 __attribute__((ext_vector_type(8)));
typedef float f32x16 __attribute__((ext_vector_type(16)));

#define ONE_BF 0x3f80

__device__ __forceinline__ unsigned short f2bf(float x) {
    unsigned u = __float_as_uint(x);
    u += 0x7fffu + ((u >> 16) & 1u);          // round-to-nearest-even
    return (unsigned short)(u >> 16);
}
__device__ __forceinline__ float bf2f(unsigned short h) {
    return __uint_as_float(((unsigned)h) << 16);
}

__global__ __launch_bounds__(256, 4) void chamfer_mfma(
    const float4* __restrict__ P, const float4* __restrict__ Q,
    unsigned* __restrict__ colpart, float* __restrict__ out)
{
    __shared__ short lAh[1024 * 8];   // A k-slots 0-7   (16 KB)
    __shared__ short lAl[1024 * 8];   // A k-slots 8-15
    __shared__ short lBh[1024 * 8];   // B k-slots 0-7
    __shared__ short lBl[1024 * 8];   // B k-slots 8-15

    const int t     = threadIdx.x;
    const int batch = blockIdx.x >> 3;
    const int bslot = blockIdx.x & 7;
    const int base  = batch << 10;

    // ---- Prologue: pack this batch's points into LDS fragments ----
#pragma unroll
    for (int i = 0; i < 4; ++i) {
        const int pt = t + (i << 8);
        {   // A side (p-points, rows)
            float4 v = P[base + pt];
            float psq = v.y * v.y + v.z * v.z + v.w * v.w;
            unsigned short psqh = f2bf(psq);
            unsigned short psql = f2bf(psq - bf2f(psqh));
            unsigned short yh = f2bf(v.y), zh = f2bf(v.z), wh = f2bf(v.w);
            unsigned short m2yh = f2bf(-2.0f * bf2f(yh));
            unsigned short m2zh = f2bf(-2.0f * bf2f(zh));
            unsigned short m2wh = f2bf(-2.0f * bf2f(wh));
            unsigned short m2yl = f2bf(-2.0f * (v.y - bf2f(yh)));
            unsigned short m2zl = f2bf(-2.0f * (v.z - bf2f(zh)));
            unsigned short m2wl = f2bf(-2.0f * (v.w - bf2f(wh)));
            bf16x8 ah = { (short)psqh, (short)psql, (short)m2yh, (short)m2zh,
                          (short)m2wh, (short)m2yl, (short)m2zl, (short)m2wl };
            bf16x8 al = { (short)m2yh, (short)m2zh, (short)m2wh,
                          (short)ONE_BF, (short)ONE_BF, 0, 0, 0 };
            *(bf16x8*)&lAh[pt * 8] = ah;
            *(bf16x8*)&lAl[pt * 8] = al;
        }
        {   // B side (q-points, cols)
            float4 v = Q[base + pt];
            float qsq = v.y * v.y + v.z * v.z + v.w * v.w;
            unsigned short qsqh = f2bf(qsq);
            unsigned short qsql = f2bf(qsq - bf2f(qsqh));
            unsigned short yh = f2bf(v.y), zh = f2bf(v.z), wh = f2bf(v.w);
            unsigned short yl = f2bf(v.y - bf2f(yh));
            unsigned short zl = f2bf(v.z - bf2f(zh));
            unsigned short wl = f2bf(v.w - bf2f(wh));
            bf16x8 bh = { (short)ONE_BF, (short)ONE_BF, (short)yh, (short)zh,
                          (short)wh, (short)yh, (short)zh, (short)wh };
            bf16x8 bl = { (short)yl, (short)zl, (short)wl,
                          (short)qsqh, (short)qsql, 0, 0, 0 };
            *(bf16x8*)&lBh[pt * 8] = bh;
            *(bf16x8*)&lBl[pt * 8] = bl;
        }
    }
    __syncthreads();

    // ---- Main loop: one 32-row strip per wave, 32 col-tiles ----
    const int lane = t & 63;
    const int half = lane >> 5;       // k-half: 0 -> slots 0-7, 1 -> 8-15
    const int l31  = lane & 31;
    const int strip = (bslot << 2) + (t >> 6);   // 0..31
    const int n0    = strip << 5;

    const short* aptr = half ? lAl : lAh;
    const short* bptr = half ? lBl : lBh;
    bf16x8 af = *(const bf16x8*)&aptr[(n0 + l31) * 8];

    f32x16 zf;
#pragma unroll
    for (int j = 0; j < 16; ++j) zf[j] = 0.0f;

    float rowacc[16];
#pragma unroll
    for (int j = 0; j < 16; ++j) rowacc[j] = 3.4e38f;

    unsigned* __restrict__ colp = colpart + (batch << 10);

    bf16x8 b0 = *(const bf16x8*)&bptr[l31 * 8];
    bf16x8 b1 = *(const bf16x8*)&bptr[(32 + l31) * 8];
    for (int m = 0; m < 32; ++m) {
        const int pf = (m + 2 < 32) ? (m + 2) : 31;
        bf16x8 bn = *(const bf16x8*)&bptr[((pf << 5) + l31) * 8];
        f32x16 c = __builtin_amdgcn_mfma_f32_32x32x16_bf16(af, b0, zf, 0, 0, 0);
        float cv = c[0];
#pragma unroll
        for (int j = 0; j < 16; ++j) rowacc[j] = fminf(rowacc[j], c[j]);
#pragma unroll
        for (int j = 1; j < 16; ++j) cv = fminf(cv, c[j]);
        cv = fmaxf(cv, 0.0f);         // clamp so uint order == float order
        atomicMin(&colp[(m << 5) + l31], __float_as_uint(cv));
        b0 = b1; b1 = bn;
    }

    // Row-min butterfly within each 32-lane half, then sqrt-sum.
#pragma unroll
    for (int mask = 1; mask <= 16; mask <<= 1) {
#pragma unroll
        for (int j = 0; j < 16; ++j)
            rowacc[j] = fminf(rowacc[j], __shfl_xor(rowacc[j], mask, 32));
    }
    float s = 0.0f;
#pragma unroll
    for (int j = 0; j < 16; ++j)
        s += sqrtf(fmaxf(rowacc[j], 0.0f) + 1e-12f);
    if (l31 == 0) atomicAdd(out, s);   // lanes 0 and 32: one per half
}

__global__ __launch_bounds__(256) void chamfer_cols(
    const unsigned* __restrict__ colpart, float* __restrict__ out)
{
    const int t = threadIdx.x;
    float s = 0.0f;
    for (int i = blockIdx.x * 256 + t; i < (1 << 17); i += 64 * 256)
        s += sqrtf(fmaxf(__uint_as_float(colpart[i]), 0.0f) + 1e-12f);
#pragma unroll
    for (int off = 32; off; off >>= 1) s += __shfl_down(s, off, 64);
    if ((t & 63) == 0) atomicAdd(out, s);
}

extern "C" void kernel_launch(void* const* d_in, const int* in_sizes, int n_in,
                              void* d_out, int out_size, void* d_ws, size_t ws_size,
                              hipStream_t stream) {
    const float4* P = (const float4*)d_in[0];
    const float4* Q = (const float4*)d_in[1];
    float* out = (float*)d_out;
    unsigned* colpart = (unsigned*)d_ws;   // 128 batches * 1024 cols = 512 KB

    hipMemsetAsync(d_out, 0, sizeof(float), stream);
    hipMemsetAsync(d_ws, 0xFF, (size_t)(1 << 17) * sizeof(unsigned), stream);
    chamfer_mfma<<<dim3(128 * 8), dim3(256), 0, stream>>>(P, Q, colpart, out);
    chamfer_cols<<<dim3(64), dim3(256), 0, stream>>>(colpart, out);
}

// Round 8
// 77.044 us; speedup vs baseline: 2.1501x; 2.1501x over previous
//
#include <hip/hip_runtime.h>

// Chamfer via MFMA, atomic-free. d2 = psq + qsq - 2 p.q in ONE
// v_mfma_f32_32x32x16_bf16 per 32x32 tile (packing PROVEN in R6, absmax 0):
//   A k-slots: {psqh, psql, -2ph(y,z,w), -2pl(y,z,w) | -2ph(y,z,w), 1, 1, 0,0,0}
//   B k-slots: {1, 1, qh(y,z,w), qh(y,z,w) | ql(y,z,w), qsqh, qsql, 0,0,0}
// Two passes over the tile space (dir=0: rows=P cols=Q; dir=1 swapped); each
// pass only needs the CHEAP in-tile reduction: min over the tile's 32 rows =
// 15-reg v_min tree + 1 shfl_xor(32) + 1 min, accumulated in a per-lane
// register (colacc) over all 32 row-tiles -> col-min fully resolved in-block.
// sqrt+sum -> block partial -> ws (non-atomic). Final kernel sums 1024
// partials -> out. NO atomics, NO memsets anywhere.
// Grid: 128 batches x 2 dirs x 4 col-blocks = 1024 blocks x 256 thr
// (4 waves; each wave owns 2 col-tiles of the block's 256 cols).
// LDS 40KB -> 4 blocks/CU. A-frags ds_read_b128 per row-tile; B-frags
// loaded once per wave.

typedef short bf16x8 __attribute__((ext_vector_type(8)));
typedef float f32x16 __attribute__((ext_vector_type(16)));

#define ONE_BF 0x3f80

__device__ __forceinline__ unsigned short f2bf(float x) {
    unsigned u = __float_as_uint(x);
    u += 0x7fffu + ((u >> 16) & 1u);          // round-to-nearest-even
    return (unsigned short)(u >> 16);
}
__device__ __forceinline__ float bf2f(unsigned short h) {
    return __uint_as_float(((unsigned)h) << 16);
}

__global__ __launch_bounds__(256, 4) void chamfer_dir(
    const float4* __restrict__ P, const float4* __restrict__ Q,
    float* __restrict__ part)
{
    __shared__ short lAh[1024 * 8];   // A k-slots 0-7  (16 KB)
    __shared__ short lAl[1024 * 8];   // A k-slots 8-15 (16 KB)
    __shared__ short lB[256 * 16];    // B interleaved [pt][half][8] (8 KB)
    __shared__ float wsum[4];

    const int blk   = blockIdx.x;
    const int batch = blk >> 3;        // 0..127
    const int dir   = (blk >> 2) & 1;  // 0: rows=P cols=Q; 1: swapped
    const int cb    = blk & 3;         // col-block (256 cols each)
    const int t     = threadIdx.x;
    const int base  = batch << 10;

    const float4* __restrict__ ownb = (dir ? Q : P) + base;   // rows
    const float4* __restrict__ oppb = (dir ? P : Q) + base;   // cols

    // ---- Pack rows (full cloud) into LDS A-fragments: 4 pts/thread ----
#pragma unroll
    for (int i = 0; i < 4; ++i) {
        const int pt = t + (i << 8);
        float4 v = ownb[pt];
        float psq = v.y * v.y + v.z * v.z + v.w * v.w;
        unsigned short psqh = f2bf(psq);
        unsigned short psql = f2bf(psq - bf2f(psqh));
        unsigned short yh = f2bf(v.y), zh = f2bf(v.z), wh = f2bf(v.w);
        unsigned short m2yh = f2bf(-2.0f * bf2f(yh));
        unsigned short m2zh = f2bf(-2.0f * bf2f(zh));
        unsigned short m2wh = f2bf(-2.0f * bf2f(wh));
        unsigned short m2yl = f2bf(-2.0f * (v.y - bf2f(yh)));
        unsigned short m2zl = f2bf(-2.0f * (v.z - bf2f(zh)));
        unsigned short m2wl = f2bf(-2.0f * (v.w - bf2f(wh)));
        bf16x8 ah = { (short)psqh, (short)psql, (short)m2yh, (short)m2zh,
                      (short)m2wh, (short)m2yl, (short)m2zl, (short)m2wl };
        bf16x8 al = { (short)m2yh, (short)m2zh, (short)m2wh,
                      (short)ONE_BF, (short)ONE_BF, 0, 0, 0 };
        *(bf16x8*)&lAh[pt * 8] = ah;
        *(bf16x8*)&lAl[pt * 8] = al;
    }
    // ---- Pack this block's 256 cols into LDS B-fragments: 1 pt/thread ----
    {
        float4 v = oppb[(cb << 8) + t];
        float qsq = v.y * v.y + v.z * v.z + v.w * v.w;
        unsigned short qsqh = f2bf(qsq);
        unsigned short qsql = f2bf(qsq - bf2f(qsqh));
        unsigned short yh = f2bf(v.y), zh = f2bf(v.z), wh = f2bf(v.w);
        unsigned short yl = f2bf(v.y - bf2f(yh));
        unsigned short zl = f2bf(v.z - bf2f(zh));
        unsigned short wl = f2bf(v.w - bf2f(wh));
        bf16x8 bh = { (short)ONE_BF, (short)ONE_BF, (short)yh, (short)zh,
                      (short)wh, (short)yh, (short)zh, (short)wh };
        bf16x8 bl = { (short)yl, (short)zl, (short)wl,
                      (short)qsqh, (short)qsql, 0, 0, 0 };
        *(bf16x8*)&lB[t * 16]     = bh;
        *(bf16x8*)&lB[t * 16 + 8] = bl;
    }
    __syncthreads();

    const int lane = t & 63;
    const int half = lane >> 5;    // k-half: 0 -> slots 0-7, 1 -> 8-15
    const int l31  = lane & 31;
    const int wv   = t >> 6;

    const short* aptr = half ? lAl : lAh;

    // Two local col-tiles per wave: c0 = wv*2, c0+1  (local cols 0..255)
    const int c0 = wv << 1;
    bf16x8 bf0 = *(const bf16x8*)&lB[(((c0 << 5) + l31) * 2 + half) * 8];
    bf16x8 bf1 = *(const bf16x8*)&lB[((((c0 + 1) << 5) + l31) * 2 + half) * 8];

    f32x16 zf;
#pragma unroll
    for (int j = 0; j < 16; ++j) zf[j] = 0.0f;

    float acc0 = 3.4e38f, acc1 = 3.4e38f;
    bf16x8 af = *(const bf16x8*)&aptr[l31 * 8];

    for (int rt = 0; rt < 32; ++rt) {
        bf16x8 afn = af;
        if (rt < 31) afn = *(const bf16x8*)&aptr[(((rt + 1) << 5) + l31) * 8];
        f32x16 ca = __builtin_amdgcn_mfma_f32_32x32x16_bf16(af, bf0, zf, 0, 0, 0);
        f32x16 cb2 = __builtin_amdgcn_mfma_f32_32x32x16_bf16(af, bf1, zf, 0, 0, 0);
        // min over the tile's 32 rows for col = l31 (both halves end equal)
        float m0 = ca[0];
#pragma unroll
        for (int j = 1; j < 16; ++j) m0 = fminf(m0, ca[j]);
        m0 = fminf(m0, __shfl_xor(m0, 32, 64));
        acc0 = fminf(acc0, m0);
        float m1 = cb2[0];
#pragma unroll
        for (int j = 1; j < 16; ++j) m1 = fminf(m1, cb2[j]);
        m1 = fminf(m1, __shfl_xor(m1, 32, 64));
        acc1 = fminf(acc1, m1);
        af = afn;
    }

    // Per-wave: sqrt + sum (half 0 only; halves are duplicates), reduce.
    float s = 0.0f;
    if (half == 0)
        s = sqrtf(fmaxf(acc0, 0.0f) + 1e-12f) + sqrtf(fmaxf(acc1, 0.0f) + 1e-12f);
#pragma unroll
    for (int off = 32; off; off >>= 1) s += __shfl_down(s, off, 64);
    if (lane == 0) wsum[wv] = s;
    __syncthreads();
    if (t == 0) part[blk] = wsum[0] + wsum[1] + wsum[2] + wsum[3];
}

__global__ __launch_bounds__(256) void chamfer_final(
    const float* __restrict__ part, float* __restrict__ out)
{
    __shared__ float ws[4];
    const int t = threadIdx.x;
    float s = part[t] + part[t + 256] + part[t + 512] + part[t + 768];
#pragma unroll
    for (int off = 32; off; off >>= 1) s += __shfl_down(s, off, 64);
    if ((t & 63) == 0) ws[t >> 6] = s;
    __syncthreads();
    if (t == 0) out[0] = ws[0] + ws[1] + ws[2] + ws[3];
}

extern "C" void kernel_launch(void* const* d_in, const int* in_sizes, int n_in,
                              void* d_out, int out_size, void* d_ws, size_t ws_size,
                              hipStream_t stream) {
    const float4* P = (const float4*)d_in[0];
    const float4* Q = (const float4*)d_in[1];
    float* out  = (float*)d_out;
    float* part = (float*)d_ws;   // 1024 block partials (4 KB)

    chamfer_dir<<<dim3(128 * 2 * 4), dim3(256), 0, stream>>>(P, Q, part);
    chamfer_final<<<dim3(1), dim3(256), 0, stream>>>(part, out);
}

// Round 9
// 70.285 us; speedup vs baseline: 2.3569x; 1.0962x over previous
//
#include <hip/hip_runtime.h>

// Chamfer via MFMA, atomic-free, loop fully de-chained.
// d2 = psq + qsq - 2 p.q in ONE v_mfma_f32_32x32x16_bf16 per 32x32 tile
// (packing PROVEN in R6/R8, absmax 0):
//   A k: {psqh,psql,-2ph(y,z,w),-2pl(y,z,w) | -2ph(y,z,w),1,1,0,0,0}
//   B k: {1,1,qh(y,z,w),qh(y,z,w) | ql(y,z,w),qsqh,qsql,0,0,0}
// Two passes over tile space (dir 0/1). Inner loop does NO reduction:
// col-partial mins accumulate ELEMENTWISE in C layout, two row-tiles per
// step folded with v_min3 (8 VALU/tile). The 16->1 tree + single
// shfl_xor(32) + sqrt run once per wave in the epilogue.
// Grid: 128 batches x 2 dirs x 4 col-blocks = 1024 blocks x 256 thr
// (4 waves x 2 col-tiles each). LDS 40KB. Partials -> ws; final kernel sums.

typedef short bf16x8 __attribute__((ext_vector_type(8)));
typedef float f32x16 __attribute__((ext_vector_type(16)));

#define ONE_BF 0x3f80

__device__ __forceinline__ unsigned short f2bf(float x) {
    unsigned u = __float_as_uint(x);
    u += 0x7fffu + ((u >> 16) & 1u);          // round-to-nearest-even
    return (unsigned short)(u >> 16);
}
__device__ __forceinline__ float bf2f(unsigned short h) {
    return __uint_as_float(((unsigned)h) << 16);
}

__global__ __launch_bounds__(256, 3) void chamfer_dir(
    const float4* __restrict__ P, const float4* __restrict__ Q,
    float* __restrict__ part)
{
    __shared__ short lAh[1024 * 8];   // A k-slots 0-7  (16 KB)
    __shared__ short lAl[1024 * 8];   // A k-slots 8-15 (16 KB)
    __shared__ short lB[256 * 16];    // B interleaved [pt][half][8] (8 KB)
    __shared__ float wsum[4];

    const int blk   = blockIdx.x;
    const int batch = blk >> 3;        // 0..127
    const int dir   = (blk >> 2) & 1;  // 0: rows=P cols=Q; 1: swapped
    const int cb    = blk & 3;         // col-block (256 cols each)
    const int t     = threadIdx.x;
    const int base  = batch << 10;

    const float4* __restrict__ ownb = (dir ? Q : P) + base;   // rows
    const float4* __restrict__ oppb = (dir ? P : Q) + base;   // cols

    // ---- Pack rows (full cloud) into LDS A-fragments: 4 pts/thread ----
#pragma unroll
    for (int i = 0; i < 4; ++i) {
        const int pt = t + (i << 8);
        float4 v = ownb[pt];
        float psq = v.y * v.y + v.z * v.z + v.w * v.w;
        unsigned short psqh = f2bf(psq);
        unsigned short psql = f2bf(psq - bf2f(psqh));
        unsigned short yh = f2bf(v.y), zh = f2bf(v.z), wh = f2bf(v.w);
        unsigned short m2yh = f2bf(-2.0f * bf2f(yh));
        unsigned short m2zh = f2bf(-2.0f * bf2f(zh));
        unsigned short m2wh = f2bf(-2.0f * bf2f(wh));
        unsigned short m2yl = f2bf(-2.0f * (v.y - bf2f(yh)));
        unsigned short m2zl = f2bf(-2.0f * (v.z - bf2f(zh)));
        unsigned short m2wl = f2bf(-2.0f * (v.w - bf2f(wh)));
        bf16x8 ah = { (short)psqh, (short)psql, (short)m2yh, (short)m2zh,
                      (short)m2wh, (short)m2yl, (short)m2zl, (short)m2wl };
        bf16x8 al = { (short)m2yh, (short)m2zh, (short)m2wh,
                      (short)ONE_BF, (short)ONE_BF, 0, 0, 0 };
        *(bf16x8*)&lAh[pt * 8] = ah;
        *(bf16x8*)&lAl[pt * 8] = al;
    }
    // ---- Pack this block's 256 cols into LDS B-fragments ----
    {
        float4 v = oppb[(cb << 8) + t];
        float qsq = v.y * v.y + v.z * v.z + v.w * v.w;
        unsigned short qsqh = f2bf(qsq);
        unsigned short qsql = f2bf(qsq - bf2f(qsqh));
        unsigned short yh = f2bf(v.y), zh = f2bf(v.z), wh = f2bf(v.w);
        unsigned short yl = f2bf(v.y - bf2f(yh));
        unsigned short zl = f2bf(v.z - bf2f(zh));
        unsigned short wl = f2bf(v.w - bf2f(wh));
        bf16x8 bh = { (short)ONE_BF, (short)ONE_BF, (short)yh, (short)zh,
                      (short)wh, (short)yh, (short)zh, (short)wh };
        bf16x8 bl = { (short)yl, (short)zl, (short)wl,
                      (short)qsqh, (short)qsql, 0, 0, 0 };
        *(bf16x8*)&lB[t * 16]     = bh;
        *(bf16x8*)&lB[t * 16 + 8] = bl;
    }
    __syncthreads();

    const int lane = t & 63;
    const int half = lane >> 5;    // k-half: 0 -> slots 0-7, 1 -> 8-15
    const int l31  = lane & 31;
    const int wv   = t >> 6;

    const short* aptr = half ? lAl : lAh;

    // Two local col-tiles per wave: c0 = wv*2, c0+1
    const int c0 = wv << 1;
    bf16x8 bf0 = *(const bf16x8*)&lB[(((c0 << 5) + l31) * 2 + half) * 8];
    bf16x8 bf1 = *(const bf16x8*)&lB[((((c0 + 1) << 5) + l31) * 2 + half) * 8];

    f32x16 zf;
#pragma unroll
    for (int j = 0; j < 16; ++j) zf[j] = 0.0f;

    f32x16 acc0, acc1;
#pragma unroll
    for (int j = 0; j < 16; ++j) { acc0[j] = 3.4e38f; acc1[j] = 3.4e38f; }

    // Inner loop: 2 row-tiles/step, elementwise min3 fold, NO reductions.
    for (int rt = 0; rt < 32; rt += 2) {
        bf16x8 af0 = *(const bf16x8*)&aptr[((rt << 5) + l31) * 8];
        bf16x8 af1 = *(const bf16x8*)&aptr[(((rt + 1) << 5) + l31) * 8];
        f32x16 ca0 = __builtin_amdgcn_mfma_f32_32x32x16_bf16(af0, bf0, zf, 0, 0, 0);
        f32x16 cb0 = __builtin_amdgcn_mfma_f32_32x32x16_bf16(af1, bf0, zf, 0, 0, 0);
        f32x16 ca1 = __builtin_amdgcn_mfma_f32_32x32x16_bf16(af0, bf1, zf, 0, 0, 0);
        f32x16 cb1 = __builtin_amdgcn_mfma_f32_32x32x16_bf16(af1, bf1, zf, 0, 0, 0);
#pragma unroll
        for (int j = 0; j < 16; ++j)
            acc0[j] = fminf(fminf(ca0[j], cb0[j]), acc0[j]);   // v_min3_f32
#pragma unroll
        for (int j = 0; j < 16; ++j)
            acc1[j] = fminf(fminf(ca1[j], cb1[j]), acc1[j]);
    }

    // Epilogue: 16->1 tree, cross-half shfl, sqrt, wave-sum, block partial.
    float m0 = acc0[0], m1 = acc1[0];
#pragma unroll
    for (int j = 1; j < 16; ++j) { m0 = fminf(m0, acc0[j]); m1 = fminf(m1, acc1[j]); }
    m0 = fminf(m0, __shfl_xor(m0, 32, 64));
    m1 = fminf(m1, __shfl_xor(m1, 32, 64));

    float s = 0.0f;
    if (half == 0)
        s = sqrtf(fmaxf(m0, 0.0f) + 1e-12f) + sqrtf(fmaxf(m1, 0.0f) + 1e-12f);
#pragma unroll
    for (int off = 32; off; off >>= 1) s += __shfl_down(s, off, 64);
    if (lane == 0) wsum[wv] = s;
    __syncthreads();
    if (t == 0) part[blk] = wsum[0] + wsum[1] + wsum[2] + wsum[3];
}

__global__ __launch_bounds__(256) void chamfer_final(
    const float* __restrict__ part, float* __restrict__ out)
{
    __shared__ float ws[4];
    const int t = threadIdx.x;
    float s = part[t] + part[t + 256] + part[t + 512] + part[t + 768];
#pragma unroll
    for (int off = 32; off; off >>= 1) s += __shfl_down(s, off, 64);
    if ((t & 63) == 0) ws[t >> 6] = s;
    __syncthreads();
    if (t == 0) out[0] = ws[0] + ws[1] + ws[2] + ws[3];
}

extern "C" void kernel_launch(void* const* d_in, const int* in_sizes, int n_in,
                              void* d_out, int out_size, void* d_ws, size_t ws_size,
                              hipStream_t stream) {
    const float4* P = (const float4*)d_in[0];
    const float4* Q = (const float4*)d_in[1];
    float* out  = (float*)d_out;
    float* part = (float*)d_ws;   // 1024 block partials (4 KB)

    chamfer_dir<<<dim3(128 * 2 * 4), dim3(256), 0, stream>>>(P, Q, part);
    chamfer_final<<<dim3(1), dim3(256), 0, stream>>>(part, out);
}